// Round 9
// baseline (5230.830 us; speedup 1.0000x reference)
//
#include <hip/hip_runtime.h>
#include <hip/hip_bf16.h>

typedef short s16x8 __attribute__((ext_vector_type(8)));
typedef float f32x4 __attribute__((ext_vector_type(4)));

__device__ __forceinline__ float bf2f(unsigned short s) {
  union { unsigned int u; float f; } c; c.u = ((unsigned int)s) << 16; return c.f;
}
__device__ __forceinline__ short f2bf(float f) {
  union { float f; unsigned int u; } c; c.f = f;
  unsigned int r = (c.u + 0x7fffu + ((c.u >> 16) & 1u)) >> 16;
  return (short)(unsigned short)r;
}
__device__ __forceinline__ float sigm(float x) { return 1.0f / (1.0f + __expf(-x)); }

__device__ __forceinline__ void gload_lds16(const short* g, short* l) {
  __builtin_amdgcn_global_load_lds((const __attribute__((address_space(1))) void*)g,
                                   (__attribute__((address_space(3))) void*)l, 16, 0, 0);
}

// 8x 16B LLC-coherent loads (bypass L1/L2)
__device__ __forceinline__ void cload8(const short* p,
    s16x8& d0, s16x8& d1, s16x8& d2, s16x8& d3,
    s16x8& d4, s16x8& d5, s16x8& d6, s16x8& d7)
{
  asm volatile(
    "global_load_dwordx4 %0, %[p], off sc0 sc1\n\t"
    "global_load_dwordx4 %1, %[p], off offset:64 sc0 sc1\n\t"
    "global_load_dwordx4 %2, %[p], off offset:128 sc0 sc1\n\t"
    "global_load_dwordx4 %3, %[p], off offset:192 sc0 sc1\n\t"
    "global_load_dwordx4 %4, %[p], off offset:256 sc0 sc1\n\t"
    "global_load_dwordx4 %5, %[p], off offset:320 sc0 sc1\n\t"
    "global_load_dwordx4 %6, %[p], off offset:384 sc0 sc1\n\t"
    "global_load_dwordx4 %7, %[p], off offset:448 sc0 sc1"
    : "=&v"(d0), "=&v"(d1), "=&v"(d2), "=&v"(d3),
      "=&v"(d4), "=&v"(d5), "=&v"(d6), "=&v"(d7)
    : [p]"v"(p) : "memory");
}

// fire-and-forget LLC-coherent 16B store
__device__ __forceinline__ void fstore16(short* p, s16x8 v) {
  asm volatile("global_store_dwordx4 %0, %1, off sc0 sc1" :: "v"(p), "v"(v) : "memory");
}

// sentinel-poll: loads the 32 A-fragments and retries until no dword is 0xFFFFFFFF.
// The accepted registers ARE the MFMA operands (no re-load).
__device__ __forceinline__ void pollA(const short* p, s16x8 (&ah)[32]) {
  for (int k = 0; k < 8192; ++k) {
    cload8(p,     ah[0], ah[1], ah[2], ah[3], ah[4], ah[5], ah[6], ah[7]);
    cload8(p+256, ah[8], ah[9], ah[10],ah[11],ah[12],ah[13],ah[14],ah[15]);
    cload8(p+512, ah[16],ah[17],ah[18],ah[19],ah[20],ah[21],ah[22],ah[23]);
    cload8(p+768, ah[24],ah[25],ah[26],ah[27],ah[28],ah[29],ah[30],ah[31]);
    asm volatile("s_waitcnt vmcnt(0)" ::: "memory");
    __builtin_amdgcn_sched_barrier(0);
    unsigned mn = 1u;
    #pragma unroll
    for (int f = 0; f < 32; ++f) {
      union { s16x8 s; unsigned u[4]; } c; c.s = ah[f];
      #pragma unroll
      for (int d = 0; d < 4; ++d) {
        unsigned v = c.u[d] ^ 0xFFFFFFFFu;
        mn = mn < v ? mn : v;
      }
    }
    if (__all(mn != 0u)) return;
  }
}

// ---------------- prep: conversions + state-buffer init (h0 + sentinels) ----------------
__global__ void prep(const float* __restrict__ x,
                     const float* __restrict__ Wfz, const float* __restrict__ Wfr, const float* __restrict__ Wfh,
                     const float* __restrict__ Wuz, const float* __restrict__ Wur, const float* __restrict__ Wuh,
                     const float* __restrict__ h0,
                     short* __restrict__ xb, short* __restrict__ Wf, short* __restrict__ Wzr,
                     short* __restrict__ Wh, short* __restrict__ sb)
{
  const long NX = 33554432L;
  const long NW = 1048576L;
  const long TOT = NX + 6*NW + 262144L;   // + h/rh state buffers
  long stride = (long)gridDim.x * blockDim.x;
  for (long p = (long)blockIdx.x * blockDim.x + threadIdx.x; p < TOT; p += stride) {
    if (p < NX) { xb[p] = f2bf(x[p]); }
    else if (p < NX + 3*NW) {
      long q = p - NX;
      float v = q < NW ? Wfz[q] : (q < 2*NW ? Wfr[q-NW] : Wfh[q-2*NW]);
      Wf[q] = f2bf(v);
    } else if (p < NX + 5*NW) {
      long q = p - NX - 3*NW;
      float v = q < NW ? Wuz[q] : Wur[q-NW];
      Wzr[q] = f2bf(v);
    } else if (p < NX + 6*NW) {
      long q = p - NX - 5*NW;
      Wh[q] = f2bf(Wuh[q]);
    } else {
      long q = p - NX - 6*NW;
      if (q < 131072) {                   // hbuf [4 dom][2 deep][16][1024]
        int dom = (int)(q >> 15), rem = (int)q & 32767;
        int deep = rem >> 14, row = (rem >> 10) & 15, cc = rem & 1023;
        sb[q] = (deep == 1) ? f2bf(h0[(dom*16+row)*1024 + cc]) : (short)0xFFFF;
      } else {                            // rhbuf: all sentinel
        sb[q] = (short)0xFFFF;
      }
    }
  }
}

// ---------------- input GEMM ----------------
__global__ __launch_bounds__(256) void gemm_x(const short* __restrict__ A, const short* __restrict__ Bw,
    const float* __restrict__ bfz, const float* __restrict__ bfr, const float* __restrict__ bfh,
    short* __restrict__ X)
{
  constexpr int M = 32768, K = 1024;
  constexpr int BM = 128, BN = 128, BK = 32;
  __shared__ __align__(16) short As[BM*BK];
  __shared__ __align__(16) short Bs[BN*BK];
  int tid = threadIdx.x, lane = tid & 63, wid = tid >> 6;
  int bm = blockIdx.x % (M/BM), bn = blockIdx.x / (M/BM);
  int wm = wid >> 1, wn = wid & 1;

  f32x4 acc[4][4];
  for (int i = 0; i < 4; ++i) for (int j = 0; j < 4; ++j) acc[i][j] = f32x4{0.f,0.f,0.f,0.f};

  int r0 = tid >> 2,        kc0 = (tid & 3) * 8;
  int r1 = (256+tid) >> 2,  kc1 = ((256+tid) & 3) * 8;
  const short* a0 = A  + (size_t)(bm*BM + r0)*K + kc0;
  const short* a1 = A  + (size_t)(bm*BM + r1)*K + kc1;
  const short* b0 = Bw + (size_t)(bn*BN + r0)*K + kc0;
  const short* b1 = Bw + (size_t)(bn*BN + r1)*K + kc1;

  const short* abase = As + (wm*64 + (lane&15))*BK + (lane>>4)*8;
  const short* bbase = Bs + (wn*64 + (lane&15))*BK + (lane>>4)*8;

  for (int k0 = 0; k0 < K; k0 += BK) {
    __syncthreads();
    gload_lds16(a0 + k0, As + wid*512);
    gload_lds16(a1 + k0, As + 2048 + wid*512);
    gload_lds16(b0 + k0, Bs + wid*512);
    gload_lds16(b1 + k0, Bs + 2048 + wid*512);
    __syncthreads();
    s16x8 af[4], bff[4];
    for (int f = 0; f < 4; ++f) {
      af[f]  = *(const s16x8*)(abase + f*16*BK);
      bff[f] = *(const s16x8*)(bbase + f*16*BK);
    }
    for (int i = 0; i < 4; ++i)
      for (int j = 0; j < 4; ++j)
        acc[i][j] = __builtin_amdgcn_mfma_f32_16x16x32_bf16(af[i], bff[j], acc[i][j], 0, 0, 0);
  }

  int col = lane & 15, rb = (lane >> 4) * 4;
  for (int fi = 0; fi < 4; ++fi) for (int fj = 0; fj < 4; ++fj) {
    int n = bn*BN + wn*64 + fj*16 + col;
    float bias = n < 1024 ? bfz[n] : (n < 2048 ? bfr[n-1024] : bfh[n-2048]);
    f32x4 c = acc[fi][fj];
    for (int i = 0; i < 4; ++i) {
      int m = bm*BM + wm*64 + fi*16 + rb + i;
      int bb = m >> 9, tt = m & 511;
      X[((size_t)tt*64 + bb)*3072 + n] = f2bf(c[i] + bias);
    }
  }
}

#define MFMA(a,b,c) __builtin_amdgcn_mfma_f32_16x16x32_bf16(a,b,c,0,0,0)

// ---------------- persistent recurrence: 256 wgs x 64 thr, barrier-free ----------------
// wg: cg = wg&63 (16 hidden cols), dom = wg>>6 (16 batch rows). All h / r*h
// exchange via LLC (sc0sc1) with SENTINEL-POLLING — no flags, no barriers, no
// drains, placement-agnostic. 2-deep buffers, poison-before-reuse protocol.
__global__ __launch_bounds__(64, 1) void recur(
  const short* __restrict__ X,    // [512][64][3072] bf16
  const short* __restrict__ Wzr,  // [2048][1024] bf16
  const short* __restrict__ Wh,   // [1024][1024] bf16
  const float* __restrict__ h0,
  const float* __restrict__ buz, const float* __restrict__ bur, const float* __restrict__ buh,
  short* hbuf,                    // [4 dom][2][16][1024] bf16 (deep1 = h0 at start)
  short* rhbuf,                   // [4 dom][2][16][1024] bf16 (all sentinel at start)
  float* y, float* hlast)
{
  __shared__ __align__(16) short Wl[3*32*64*8];   // 98304 B, fragment-ordered
  __shared__ __align__(16) short tile[256];       // 16x16 transpose bounce

  int wg = blockIdx.x;
  int cg = wg & 63, dom = wg >> 6;
  int lane = threadIdx.x;
  int col = lane & 15, hi = lane >> 4;
  int kfo = hi*8, rb = hi*4;
  int j = cg*16 + col;              // owned hidden column
  int trow = lane >> 1, tfr = lane & 1;
  int tOff = trow*1024 + cg*16 + tfr*8;   // this lane's 16B fragment in [16][1024]
  int aOff = col*1024 + kfo;              // A-operand fragment base (row=col, k=kfo)

  // ---- stage weights -> LDS (fragment-ordered [gate][chunk][lane][8]) ----
  {
    const short* g0 = Wzr + (size_t)j*1024 + kfo;
    const short* g1 = Wzr + (size_t)(1024+j)*1024 + kfo;
    const short* g2 = Wh  + (size_t)j*1024 + kfo;
    #pragma unroll 4
    for (int n = 0; n < 32; ++n) {
      *(s16x8*)(Wl + ((0*32+n)*64 + lane)*8) = *(const s16x8*)(g0 + n*32);
      *(s16x8*)(Wl + ((1*32+n)*64 + lane)*8) = *(const s16x8*)(g1 + n*32);
      *(s16x8*)(Wl + ((2*32+n)*64 + lane)*8) = *(const s16x8*)(g2 + n*32);
    }
  }

  float bz = buz[j], br = bur[j], bh = buh[j];
  float hreg[4], zreg[4];
  #pragma unroll
  for (int i = 0; i < 4; ++i) hreg[i] = h0[(dom*16 + rb + i)*1024 + j];

  short* hB = hbuf  + dom*32768;    // [2][16][1024]
  short* rB = rhbuf + dom*32768;

  s16x8 sent;
  #pragma unroll
  for (int k = 0; k < 8; ++k) sent[k] = (short)0xFFFF;

  // X(0)
  unsigned short xv[12];
  {
    const unsigned short* Xu = (const unsigned short*)X;
    #pragma unroll
    for (int i = 0; i < 4; ++i) {
      size_t base = (size_t)(dom*16 + rb + i)*3072 + j;
      xv[i] = Xu[base]; xv[4+i] = Xu[base+1024]; xv[8+i] = Xu[base+2048];
    }
  }

  const short* wlz = Wl + lane*8;
  const short* wlr = Wl + 16384 + lane*8;
  const short* wlh = Wl + 32768 + lane*8;

  s16x8 ah[32];

  for (int t = 0; t < 512; ++t) {
    short* hW       = hB + (t&1)*16384;        // h(t) write target (holds stale h(t-2))
    const short* hR = hB + ((t+1)&1)*16384;    // h(t-1)
    short* rW       = rB + (t&1)*16384;        // rh(t) write target
    short* rP       = rB + ((t+1)&1)*16384;    // rh buf to poison (reused at t+1)

    // poison own slice of h-write buffer (safe: rh(t-1) accepted last step =>
    // all wgs finished reading h(t-2)); drained by the P1 poll below.
    if (lane < 32) fstore16(hW + tOff, sent);

    // ---- phase 1: poll h(t-1), compute z & r, publish rh(t) ----
    pollA(hR + aOff, ah);
    f32x4 acz0 = {0.f,0.f,0.f,0.f}, acz1 = {0.f,0.f,0.f,0.f};
    f32x4 acr0 = {0.f,0.f,0.f,0.f}, acr1 = {0.f,0.f,0.f,0.f};
    #pragma unroll
    for (int n = 0; n < 32; ++n) {
      s16x8 vz = *(const s16x8*)(wlz + n*512);
      s16x8 vr = *(const s16x8*)(wlr + n*512);
      if (n&1) { acz1 = MFMA(ah[n], vz, acz1); acr1 = MFMA(ah[n], vr, acr1); }
      else     { acz0 = MFMA(ah[n], vz, acz0); acr0 = MFMA(ah[n], vr, acr0); }
    }
    #pragma unroll
    for (int i = 0; i < 4; ++i) {
      zreg[i] = sigm(bf2f(xv[i]) + acz0[i] + acz1[i] + bz);
      float rv = sigm(bf2f(xv[4+i]) + acr0[i] + acr1[i] + br);
      tile[(rb+i)*16 + col] = f2bf(rv * hreg[i]);
    }
    if (lane < 32) {
      s16x8 tv = *(const s16x8*)(tile + trow*16 + tfr*8);
      fstore16(rW + tOff, tv);                 // fire-and-forget
      fstore16(rP + tOff, sent);               // poison next rh buffer (safe: h(t-1)
    }                                          // accepted => all read rh(t-1))

    // ---- phase 2: poll rh(t), compute h_hat, combine, publish h(t) ----
    pollA(rW + aOff, ah);
    f32x4 ach0 = {0.f,0.f,0.f,0.f}, ach1 = {0.f,0.f,0.f,0.f};
    #pragma unroll
    for (int n = 0; n < 32; ++n) {
      s16x8 vh = *(const s16x8*)(wlh + n*512);
      if (n&1) ach1 = MFMA(ah[n], vh, ach1); else ach0 = MFMA(ah[n], vh, ach0);
    }
    #pragma unroll
    for (int i = 0; i < 4; ++i) {
      float s  = bf2f(xv[8+i]) + ach0[i] + ach1[i] + bh;
      float hh = s * sigm(s);
      float hn = (1.0f - zreg[i])*hreg[i] + zreg[i]*hh;
      hreg[i] = hn;
      y[((size_t)(dom*16 + rb + i)*512 + t)*1024 + j] = hn;
      tile[(rb+i)*16 + col] = f2bf(hn);
    }
    if (lane < 32) {
      s16x8 tv = *(const s16x8*)(tile + trow*16 + tfr*8);
      fstore16(hW + tOff, tv);                 // fire-and-forget publish h(t)
    }
    if (t == 511) {
      #pragma unroll
      for (int i = 0; i < 4; ++i) hlast[(dom*16 + rb + i)*1024 + j] = hreg[i];
    } else {
      // X(t+1) prefetch (plain cached loads; drained by next P1 poll)
      const unsigned short* Xu = (const unsigned short*)X;
      #pragma unroll
      for (int i = 0; i < 4; ++i) {
        size_t base = ((size_t)(t+1)*64 + dom*16 + rb + i)*3072 + j;
        xv[i] = Xu[base]; xv[4+i] = Xu[base+1024]; xv[8+i] = Xu[base+2048];
      }
    }
  }
}

extern "C" void kernel_launch(void* const* d_in, const int* in_sizes, int n_in,
                              void* d_out, int out_size, void* d_ws, size_t ws_size,
                              hipStream_t stream) {
  const float* x   = (const float*)d_in[0];
  const float* h0  = (const float*)d_in[1];
  const float* Wfz = (const float*)d_in[2];
  const float* bfz = (const float*)d_in[3];
  const float* Wfr = (const float*)d_in[4];
  const float* bfr = (const float*)d_in[5];
  const float* Wfh = (const float*)d_in[6];
  const float* bfh = (const float*)d_in[7];
  const float* Wuz = (const float*)d_in[8];
  const float* buz = (const float*)d_in[9];
  const float* Wur = (const float*)d_in[10];
  const float* bur = (const float*)d_in[11];
  const float* Wuh = (const float*)d_in[12];
  const float* buh = (const float*)d_in[13];

  char* ws = (char*)d_ws;
  short* Xb  = (short*)(ws);                  // 201326592 B  [512][64][3072] bf16
  short* xb  = (short*)(ws + 201326592);      //  67108864 B
  short* Wf  = (short*)(ws + 268435456);      //   6291456 B
  short* Wzr = (short*)(ws + 274726912);      //   4194304 B
  short* Wh  = (short*)(ws + 278921216);      //   2097152 B
  short* sb  = (short*)(ws + 281018368);      //    524288 B: hbuf[131072] + rhbuf[131072] shorts
  short* hbuf  = sb;
  short* rhbuf = sb + 131072;

  float* y = (float*)d_out;
  float* hlast = y + 33554432;

  prep<<<2048, 256, 0, stream>>>(x, Wfz, Wfr, Wfh, Wuz, Wur, Wuh, h0, xb, Wf, Wzr, Wh, sb);
  gemm_x<<<6144, 256, 0, stream>>>(xb, Wf, bfz, bfr, bfh, Xb);
  recur<<<256, 64, 0, stream>>>(Xb, Wzr, Wh, h0, buz, bur, buh, hbuf, rhbuf, y, hlast);
}

// Round 11
// 4365.264 us; speedup vs baseline: 1.1983x; 1.1983x over previous
//
#include <hip/hip_runtime.h>
#include <hip/hip_bf16.h>

typedef short s16x8 __attribute__((ext_vector_type(8)));
typedef float f32x4 __attribute__((ext_vector_type(4)));

__device__ __forceinline__ float bf2f(unsigned short s) {
  union { unsigned int u; float f; } c; c.u = ((unsigned int)s) << 16; return c.f;
}
__device__ __forceinline__ short f2bf(float f) {
  union { float f; unsigned int u; } c; c.f = f;
  unsigned int r = (c.u + 0x7fffu + ((c.u >> 16) & 1u)) >> 16;
  return (short)(unsigned short)r;
}
__device__ __forceinline__ float sigm(float x) { return 1.0f / (1.0f + __expf(-x)); }

__device__ __forceinline__ void gload_lds16(const short* g, short* l) {
  __builtin_amdgcn_global_load_lds((const __attribute__((address_space(1))) void*)g,
                                   (__attribute__((address_space(3))) void*)l, 16, 0, 0);
}

#define SB() __builtin_amdgcn_sched_barrier(0)
#define WAITV(N) asm volatile("s_waitcnt vmcnt(" #N ")" ::: "memory"); SB();

// 8x 16B LLC-coherent loads (bypass L1/L2)
__device__ __forceinline__ void cload8(const short* p,
    s16x8& d0, s16x8& d1, s16x8& d2, s16x8& d3,
    s16x8& d4, s16x8& d5, s16x8& d6, s16x8& d7)
{
  asm volatile(
    "global_load_dwordx4 %0, %[p], off sc0 sc1\n\t"
    "global_load_dwordx4 %1, %[p], off offset:64 sc0 sc1\n\t"
    "global_load_dwordx4 %2, %[p], off offset:128 sc0 sc1\n\t"
    "global_load_dwordx4 %3, %[p], off offset:192 sc0 sc1\n\t"
    "global_load_dwordx4 %4, %[p], off offset:256 sc0 sc1\n\t"
    "global_load_dwordx4 %5, %[p], off offset:320 sc0 sc1\n\t"
    "global_load_dwordx4 %6, %[p], off offset:384 sc0 sc1\n\t"
    "global_load_dwordx4 %7, %[p], off offset:448 sc0 sc1"
    : "=&v"(d0), "=&v"(d1), "=&v"(d2), "=&v"(d3),
      "=&v"(d4), "=&v"(d5), "=&v"(d6), "=&v"(d7)
    : [p]"v"(p) : "memory");
}

// fire-and-forget LLC-coherent 16B store
__device__ __forceinline__ void fstore16(short* p, s16x8 v) {
  asm volatile("global_store_dwordx4 %0, %1, off sc0 sc1" :: "v"(p), "v"(v) : "memory");
}
// fire-and-forget LLC-coherent 4B store
__device__ __forceinline__ void fstore4(int* p, int v) {
  asm volatile("global_store_dword %0, %1, off sc0 sc1" :: "v"(p), "v"(v) : "memory");
}

// sentinel-poll: load 32 A-fragments, retry until no dword is 0xFFFFFFFF.
// Accepted registers ARE the MFMA operands.
__device__ __forceinline__ void pollA(const short* p, s16x8 (&ah)[32]) {
  for (int k = 0; k < 4096; ++k) {
    cload8(p,     ah[0], ah[1], ah[2], ah[3], ah[4], ah[5], ah[6], ah[7]);
    cload8(p+256, ah[8], ah[9], ah[10],ah[11],ah[12],ah[13],ah[14],ah[15]);
    cload8(p+512, ah[16],ah[17],ah[18],ah[19],ah[20],ah[21],ah[22],ah[23]);
    cload8(p+768, ah[24],ah[25],ah[26],ah[27],ah[28],ah[29],ah[30],ah[31]);
    asm volatile("s_waitcnt vmcnt(0)" ::: "memory");
    __builtin_amdgcn_sched_barrier(0);
    unsigned mn = 1u;
    #pragma unroll
    for (int f = 0; f < 32; ++f) {
      union { s16x8 s; unsigned u[4]; } c; c.s = ah[f];
      #pragma unroll
      for (int d = 0; d < 4; ++d) {
        unsigned v = c.u[d] ^ 0xFFFFFFFFu;
        mn = mn < v ? mn : v;
      }
    }
    if (__all(mn != 0u)) return;
  }
}

// ---------------- prep: conversions + state-buffer init ----------------
__global__ void prep(const float* __restrict__ x,
                     const float* __restrict__ Wfz, const float* __restrict__ Wfr, const float* __restrict__ Wfh,
                     const float* __restrict__ Wuz, const float* __restrict__ Wur, const float* __restrict__ Wuh,
                     const float* __restrict__ h0,
                     short* __restrict__ xb, short* __restrict__ Wf, short* __restrict__ Wzr,
                     short* __restrict__ Wh, short* __restrict__ sb)
{
  const long NX = 33554432L;
  const long NW = 1048576L;
  const long TOT = NX + 6*NW + 262144L;
  long stride = (long)gridDim.x * blockDim.x;
  for (long p = (long)blockIdx.x * blockDim.x + threadIdx.x; p < TOT; p += stride) {
    if (p < NX) { xb[p] = f2bf(x[p]); }
    else if (p < NX + 3*NW) {
      long q = p - NX;
      float v = q < NW ? Wfz[q] : (q < 2*NW ? Wfr[q-NW] : Wfh[q-2*NW]);
      Wf[q] = f2bf(v);
    } else if (p < NX + 5*NW) {
      long q = p - NX - 3*NW;
      float v = q < NW ? Wuz[q] : Wur[q-NW];
      Wzr[q] = f2bf(v);
    } else if (p < NX + 6*NW) {
      long q = p - NX - 5*NW;
      Wh[q] = f2bf(Wuh[q]);
    } else {
      long q = p - NX - 6*NW;
      if (q < 131072) {                 // hbuf [4 dom][2][16][1024]; deep0 = h0
        int dom = (int)(q >> 15), rem = (int)q & 32767;
        int deep = rem >> 14, row = (rem >> 10) & 15, cc = rem & 1023;
        sb[q] = (deep == 0) ? f2bf(h0[(dom*16+row)*1024 + cc]) : (short)0;
      } else {                          // rhbuf: all sentinel
        sb[q] = (short)0xFFFF;
      }
    }
  }
}

// ---------------- input GEMM ----------------
__global__ __launch_bounds__(256) void gemm_x(const short* __restrict__ A, const short* __restrict__ Bw,
    const float* __restrict__ bfz, const float* __restrict__ bfr, const float* __restrict__ bfh,
    short* __restrict__ X)
{
  constexpr int M = 32768, K = 1024;
  constexpr int BM = 128, BN = 128, BK = 32;
  __shared__ __align__(16) short As[BM*BK];
  __shared__ __align__(16) short Bs[BN*BK];
  int tid = threadIdx.x, lane = tid & 63, wid = tid >> 6;
  int bm = blockIdx.x % (M/BM), bn = blockIdx.x / (M/BM);
  int wm = wid >> 1, wn = wid & 1;

  f32x4 acc[4][4];
  for (int i = 0; i < 4; ++i) for (int j = 0; j < 4; ++j) acc[i][j] = f32x4{0.f,0.f,0.f,0.f};

  int r0 = tid >> 2,        kc0 = (tid & 3) * 8;
  int r1 = (256+tid) >> 2,  kc1 = ((256+tid) & 3) * 8;
  const short* a0 = A  + (size_t)(bm*BM + r0)*K + kc0;
  const short* a1 = A  + (size_t)(bm*BM + r1)*K + kc1;
  const short* b0 = Bw + (size_t)(bn*BN + r0)*K + kc0;
  const short* b1 = Bw + (size_t)(bn*BN + r1)*K + kc1;

  const short* abase = As + (wm*64 + (lane&15))*BK + (lane>>4)*8;
  const short* bbase = Bs + (wn*64 + (lane&15))*BK + (lane>>4)*8;

  for (int k0 = 0; k0 < K; k0 += BK) {
    __syncthreads();
    gload_lds16(a0 + k0, As + wid*512);
    gload_lds16(a1 + k0, As + 2048 + wid*512);
    gload_lds16(b0 + k0, Bs + wid*512);
    gload_lds16(b1 + k0, Bs + 2048 + wid*512);
    __syncthreads();
    s16x8 af[4], bff[4];
    for (int f = 0; f < 4; ++f) {
      af[f]  = *(const s16x8*)(abase + f*16*BK);
      bff[f] = *(const s16x8*)(bbase + f*16*BK);
    }
    for (int i = 0; i < 4; ++i)
      for (int j = 0; j < 4; ++j)
        acc[i][j] = __builtin_amdgcn_mfma_f32_16x16x32_bf16(af[i], bff[j], acc[i][j], 0, 0, 0);
  }

  int col = lane & 15, rb = (lane >> 4) * 4;
  for (int fi = 0; fi < 4; ++fi) for (int fj = 0; fj < 4; ++fj) {
    int n = bn*BN + wn*64 + fj*16 + col;
    float bias = n < 1024 ? bfz[n] : (n < 2048 ? bfr[n-1024] : bfh[n-2048]);
    f32x4 c = acc[fi][fj];
    for (int i = 0; i < 4; ++i) {
      int m = bm*BM + wm*64 + fi*16 + rb + i;
      int bb = m >> 9, tt = m & 511;
      X[((size_t)tt*64 + bb)*3072 + n] = f2bf(c[i] + bias);
    }
  }
}

#define MFMA(a,b,c) __builtin_amdgcn_mfma_f32_16x16x32_bf16(a,b,c,0,0,0)

// ---------------- persistent recurrence: 256 wgs x 64 thr ----------------
// cg = wg&63 (16 cols), bg = wg>>6 (16 batch rows). ONE flag-barrier per step
// (h exchange); rh exchange is sentinel-polled. 2-deep rh buffers; the old
// rh buffer is poisoned ONLY AFTER the flag-poll proves all wgs finished
// reading it (this was round 10's race).
__global__ __launch_bounds__(64, 1) void recur(
  const short* __restrict__ X,    // [512][64][3072] bf16
  const short* __restrict__ Wzr,  // [2048][1024] bf16
  const short* __restrict__ Wh,   // [1024][1024] bf16
  const float* __restrict__ h0,
  const float* __restrict__ buz, const float* __restrict__ bur, const float* __restrict__ buh,
  short* hbuf,                    // [4 dom][2][16][1024] bf16 (deep0 = h0)
  short* rhbuf,                   // [4 dom][2][16][1024] bf16 (all sentinel)
  float* y, float* hlast, int* flags)
{
  __shared__ __align__(16) short Wl[3*32*64*8];   // 98304 B, fragment-ordered
  __shared__ __align__(16) short tile[256];       // 16x16 transpose bounce

  int wg = blockIdx.x;
  int cg = wg & 63, bg = wg >> 6;
  int lane = threadIdx.x;
  int col = lane & 15, hi = lane >> 4;
  int kfo = hi*8, rb = hi*4;
  int j = cg*16 + col;
  int trow = lane >> 1, tfr = lane & 1;
  int tOff = trow*1024 + cg*16 + tfr*8;   // this wg's 16B fragment in [16][1024]
  int aOff = col*1024 + kfo;              // A-operand fragment base

  // ---- stage weights -> LDS (fragment-ordered; lane-local, no sync needed) ----
  {
    const short* g0 = Wzr + (size_t)j*1024 + kfo;
    const short* g1 = Wzr + (size_t)(1024+j)*1024 + kfo;
    const short* g2 = Wh  + (size_t)j*1024 + kfo;
    #pragma unroll 4
    for (int n = 0; n < 32; ++n) {
      *(s16x8*)(Wl + ((0*32+n)*64 + lane)*8) = *(const s16x8*)(g0 + n*32);
      *(s16x8*)(Wl + ((1*32+n)*64 + lane)*8) = *(const s16x8*)(g1 + n*32);
      *(s16x8*)(Wl + ((2*32+n)*64 + lane)*8) = *(const s16x8*)(g2 + n*32);
    }
  }

  float bz = buz[j], br = bur[j], bh = buh[j];
  float hreg[4], zreg[4], hnv[4];
  #pragma unroll
  for (int i = 0; i < 4; ++i) hreg[i] = h0[(bg*16 + rb + i)*1024 + j];

  short* hB = hbuf  + bg*32768;   // [2][16][1024]
  short* rB = rhbuf + bg*32768;
  int* fslot = flags + wg*32;
  const int* fpoll = flags + (bg*64 + lane)*32;

  s16x8 sent;
  #pragma unroll
  for (int k = 0; k < 8; ++k) sent[k] = (short)0xFFFF;

  const short* wlz = Wl + lane*8;
  const short* wlr = Wl + 16384 + lane*8;
  const short* wlh = Wl + 32768 + lane*8;

  s16x8 ah[32];
  unsigned short xv[12];

  for (int t = 0; t < 512; ++t) {
    const short* hbc = hB + (t&1)*16384;         // h(t-1)
    short* hW        = hB + ((t+1)&1)*16384;     // h(t) target
    short* rW        = rB + (t&1)*16384;         // rh(t) target (pre-poisoned)
    short* rP        = rB + ((t+1)&1)*16384;     // rh(t-1) buffer, recycled for t+1

    // ===== barrier (once per step): drain h(t-1) store, flag, shadow, poll =====
    asm volatile("s_waitcnt vmcnt(0)" ::: "memory");
    if (lane == 0) fstore4(fslot, t+1);
    // shadow work (no shared-buffer writes here!):
    if (t) {
      #pragma unroll
      for (int i = 0; i < 4; ++i)
        __builtin_nontemporal_store(hnv[i], y + ((size_t)(bg*16 + rb + i)*512 + (t-1))*1024 + j);
    }
    {
      const unsigned short* Xu = (const unsigned short*)X;
      #pragma unroll
      for (int i = 0; i < 4; ++i) {
        size_t base = ((size_t)t*64 + bg*16 + rb + i)*3072 + j;
        xv[i] = Xu[base]; xv[4+i] = Xu[base+1024]; xv[8+i] = Xu[base+2048];
      }
    }
    {
      int v; unsigned k = 0;
      do {
        asm volatile("global_load_dword %0, %1, off sc0 sc1\n\ts_waitcnt vmcnt(0)"
                     : "=v"(v) : "v"(fpoll) : "memory");
      } while (!__all(v >= t+1) && ++k < (1u<<15));
    }
    // poll success => every wg finished reading rh(t-1): NOW safe to poison.
    // (Drained by P1's WAITV(0) below, hence globally visible before any
    // wg can write rh(t+1) into this buffer — that requires flags >= t+2.)
    if (lane < 32) fstore16(rP + tOff, sent);

    // ===== phase 1: ingest h(t-1), compute z & r, publish rh(t) =====
    {
      const short* ap = hbc + aOff;
      cload8(ap,     ah[0], ah[1], ah[2], ah[3], ah[4], ah[5], ah[6], ah[7]);
      cload8(ap+256, ah[8], ah[9], ah[10],ah[11],ah[12],ah[13],ah[14],ah[15]);
      cload8(ap+512, ah[16],ah[17],ah[18],ah[19],ah[20],ah[21],ah[22],ah[23]);
      cload8(ap+768, ah[24],ah[25],ah[26],ah[27],ah[28],ah[29],ah[30],ah[31]);
      WAITV(0)
      f32x4 acz0 = {0.f,0.f,0.f,0.f}, acz1 = {0.f,0.f,0.f,0.f};
      f32x4 acr0 = {0.f,0.f,0.f,0.f}, acr1 = {0.f,0.f,0.f,0.f};
      #pragma unroll
      for (int n = 0; n < 32; ++n) {
        s16x8 vz = *(const s16x8*)(wlz + n*512);
        s16x8 vr = *(const s16x8*)(wlr + n*512);
        if (n&1) { acz1 = MFMA(ah[n], vz, acz1); acr1 = MFMA(ah[n], vr, acr1); }
        else     { acz0 = MFMA(ah[n], vz, acz0); acr0 = MFMA(ah[n], vr, acr0); }
      }
      #pragma unroll
      for (int i = 0; i < 4; ++i) {
        zreg[i] = sigm(bf2f(xv[i]) + acz0[i] + acz1[i] + bz);
        float rv = sigm(bf2f(xv[4+i]) + acr0[i] + acr1[i] + br);
        tile[(rb+i)*16 + col] = f2bf(rv * hreg[i]);
      }
      if (lane < 32) {
        s16x8 tv = *(const s16x8*)(tile + trow*16 + tfr*8);
        fstore16(rW + tOff, tv);
      }
      // drain own rh store before polling peers
      asm volatile("s_waitcnt vmcnt(0)" ::: "memory");
    }

    // ===== phase 2: sentinel-poll rh(t), compute h_hat, combine, publish h(t) =====
    pollA(rW + aOff, ah);
    {
      f32x4 ach0 = {0.f,0.f,0.f,0.f}, ach1 = {0.f,0.f,0.f,0.f};
      #pragma unroll
      for (int n = 0; n < 32; ++n) {
        s16x8 vh = *(const s16x8*)(wlh + n*512);
        if (n&1) ach1 = MFMA(ah[n], vh, ach1); else ach0 = MFMA(ah[n], vh, ach0);
      }
      #pragma unroll
      for (int i = 0; i < 4; ++i) {
        float s  = bf2f(xv[8+i]) + ach0[i] + ach1[i] + bh;
        float hh = s * sigm(s);
        float hn = (1.0f - zreg[i])*hreg[i] + zreg[i]*hh;
        hreg[i] = hn; hnv[i] = hn;
        tile[(rb+i)*16 + col] = f2bf(hn);
      }
      if (lane < 32) {
        s16x8 tv = *(const s16x8*)(tile + trow*16 + tfr*8);
        fstore16(hW + tOff, tv);   // fire-and-forget; drained at next step's barrier
      }
    }
  }

  // epilogue: y(511) + hlast
  #pragma unroll
  for (int i = 0; i < 4; ++i) {
    __builtin_nontemporal_store(hnv[i], y + ((size_t)(bg*16 + rb + i)*512 + 511)*1024 + j);
    hlast[(bg*16 + rb + i)*1024 + j] = hreg[i];
  }
}

extern "C" void kernel_launch(void* const* d_in, const int* in_sizes, int n_in,
                              void* d_out, int out_size, void* d_ws, size_t ws_size,
                              hipStream_t stream) {
  const float* x   = (const float*)d_in[0];
  const float* h0  = (const float*)d_in[1];
  const float* Wfz = (const float*)d_in[2];
  const float* bfz = (const float*)d_in[3];
  const float* Wfr = (const float*)d_in[4];
  const float* bfr = (const float*)d_in[5];
  const float* Wfh = (const float*)d_in[6];
  const float* bfh = (const float*)d_in[7];
  const float* Wuz = (const float*)d_in[8];
  const float* buz = (const float*)d_in[9];
  const float* Wur = (const float*)d_in[10];
  const float* bur = (const float*)d_in[11];
  const float* Wuh = (const float*)d_in[12];
  const float* buh = (const float*)d_in[13];

  char* ws = (char*)d_ws;
  short* Xb  = (short*)(ws);                  // 201326592 B  [512][64][3072] bf16
  short* xb  = (short*)(ws + 201326592);      //  67108864 B
  short* Wf  = (short*)(ws + 268435456);      //   6291456 B
  short* Wzr = (short*)(ws + 274726912);      //   4194304 B
  short* Wh  = (short*)(ws + 278921216);      //   2097152 B
  short* sb  = (short*)(ws + 281018368);      //    524288 B: hbuf + rhbuf
  short* hbuf  = sb;
  short* rhbuf = sb + 131072;
  int*   bar = (int*)(ws + 281542656);        //  32768 B flags[256*32]

  float* y = (float*)d_out;
  float* hlast = y + 33554432;

  hipMemsetAsync(bar, 0, 32768, stream);
  prep<<<2048, 256, 0, stream>>>(x, Wfz, Wfr, Wfh, Wuz, Wur, Wuh, h0, xb, Wf, Wzr, Wh, sb);
  gemm_x<<<6144, 256, 0, stream>>>(xb, Wf, bfz, bfr, bfh, Xb);
  recur<<<256, 64, 0, stream>>>(Xb, Wzr, Wh, h0, buz, bur, buh, hbuf, rhbuf, y, hlast, bar);
}

// Round 12
// 3763.110 us; speedup vs baseline: 1.3900x; 1.1600x over previous
//
#include <hip/hip_runtime.h>
#include <hip/hip_bf16.h>

typedef short s16x8 __attribute__((ext_vector_type(8)));
typedef float f32x4 __attribute__((ext_vector_type(4)));

__device__ __forceinline__ float bf2f(unsigned short s) {
  union { unsigned int u; float f; } c; c.u = ((unsigned int)s) << 16; return c.f;
}
__device__ __forceinline__ short f2bf(float f) {
  union { float f; unsigned int u; } c; c.f = f;
  unsigned int r = (c.u + 0x7fffu + ((c.u >> 16) & 1u)) >> 16;
  return (short)(unsigned short)r;
}
__device__ __forceinline__ float sigm(float x) { return 1.0f / (1.0f + __expf(-x)); }

__device__ __forceinline__ void gload_lds16(const short* g, short* l) {
  __builtin_amdgcn_global_load_lds((const __attribute__((address_space(1))) void*)g,
                                   (__attribute__((address_space(3))) void*)l, 16, 0, 0);
}

#define SB() __builtin_amdgcn_sched_barrier(0)
#define WAITV(N) asm volatile("s_waitcnt vmcnt(" #N ")" ::: "memory"); SB();

// batched coherent loads: 8x global_load_dwordx4 sc0 sc1 (LLC)
__device__ __forceinline__ void cload8(const short* p,
    s16x8& d0, s16x8& d1, s16x8& d2, s16x8& d3,
    s16x8& d4, s16x8& d5, s16x8& d6, s16x8& d7)
{
  asm volatile(
    "global_load_dwordx4 %0, %[p], off sc0 sc1\n\t"
    "global_load_dwordx4 %1, %[p], off offset:64 sc0 sc1\n\t"
    "global_load_dwordx4 %2, %[p], off offset:128 sc0 sc1\n\t"
    "global_load_dwordx4 %3, %[p], off offset:192 sc0 sc1\n\t"
    "global_load_dwordx4 %4, %[p], off offset:256 sc0 sc1\n\t"
    "global_load_dwordx4 %5, %[p], off offset:320 sc0 sc1\n\t"
    "global_load_dwordx4 %6, %[p], off offset:384 sc0 sc1\n\t"
    "global_load_dwordx4 %7, %[p], off offset:448 sc0 sc1"
    : "=&v"(d0), "=&v"(d1), "=&v"(d2), "=&v"(d3),
      "=&v"(d4), "=&v"(d5), "=&v"(d6), "=&v"(d7)
    : [p]"v"(p) : "memory");
}

// ---------------- prep ----------------
__global__ void prep(const float* __restrict__ x,
                     const float* __restrict__ Wfz, const float* __restrict__ Wfr, const float* __restrict__ Wfh,
                     const float* __restrict__ Wuz, const float* __restrict__ Wur, const float* __restrict__ Wuh,
                     const float* __restrict__ h0,
                     short* __restrict__ xb, short* __restrict__ Wf, short* __restrict__ Wzr,
                     short* __restrict__ Wh, short* __restrict__ hb)
{
  const long NX = 33554432L;
  const long NW = 1048576L;
  const long TOT = NX + 6*NW + 65536L;
  long stride = (long)gridDim.x * blockDim.x;
  for (long p = (long)blockIdx.x * blockDim.x + threadIdx.x; p < TOT; p += stride) {
    if (p < NX) { xb[p] = f2bf(x[p]); }
    else if (p < NX + 3*NW) {
      long q = p - NX;
      float v = q < NW ? Wfz[q] : (q < 2*NW ? Wfr[q-NW] : Wfh[q-2*NW]);
      Wf[q] = f2bf(v);
    } else if (p < NX + 5*NW) {
      long q = p - NX - 3*NW;
      float v = q < NW ? Wuz[q] : Wur[q-NW];
      Wzr[q] = f2bf(v);
    } else if (p < NX + 6*NW) {
      long q = p - NX - 5*NW;
      Wh[q] = f2bf(Wuh[q]);
    } else {
      long q = p - NX - 6*NW;
      hb[q] = f2bf(h0[q]);
    }
  }
}

// ---------------- input GEMM ----------------
__global__ __launch_bounds__(256) void gemm_x(const short* __restrict__ A, const short* __restrict__ Bw,
    const float* __restrict__ bfz, const float* __restrict__ bfr, const float* __restrict__ bfh,
    short* __restrict__ X)
{
  constexpr int M = 32768, K = 1024;
  constexpr int BM = 128, BN = 128, BK = 32;
  __shared__ __align__(16) short As[BM*BK];
  __shared__ __align__(16) short Bs[BN*BK];
  int tid = threadIdx.x, lane = tid & 63, wid = tid >> 6;
  int bm = blockIdx.x % (M/BM), bn = blockIdx.x / (M/BM);
  int wm = wid >> 1, wn = wid & 1;

  f32x4 acc[4][4];
  for (int i = 0; i < 4; ++i) for (int j = 0; j < 4; ++j) acc[i][j] = f32x4{0.f,0.f,0.f,0.f};

  int r0 = tid >> 2,        kc0 = (tid & 3) * 8;
  int r1 = (256+tid) >> 2,  kc1 = ((256+tid) & 3) * 8;
  const short* a0 = A  + (size_t)(bm*BM + r0)*K + kc0;
  const short* a1 = A  + (size_t)(bm*BM + r1)*K + kc1;
  const short* b0 = Bw + (size_t)(bn*BN + r0)*K + kc0;
  const short* b1 = Bw + (size_t)(bn*BN + r1)*K + kc1;

  const short* abase = As + (wm*64 + (lane&15))*BK + (lane>>4)*8;
  const short* bbase = Bs + (wn*64 + (lane&15))*BK + (lane>>4)*8;

  for (int k0 = 0; k0 < K; k0 += BK) {
    __syncthreads();
    gload_lds16(a0 + k0, As + wid*512);
    gload_lds16(a1 + k0, As + 2048 + wid*512);
    gload_lds16(b0 + k0, Bs + wid*512);
    gload_lds16(b1 + k0, Bs + 2048 + wid*512);
    __syncthreads();
    s16x8 af[4], bff[4];
    for (int f = 0; f < 4; ++f) {
      af[f]  = *(const s16x8*)(abase + f*16*BK);
      bff[f] = *(const s16x8*)(bbase + f*16*BK);
    }
    for (int i = 0; i < 4; ++i)
      for (int j = 0; j < 4; ++j)
        acc[i][j] = __builtin_amdgcn_mfma_f32_16x16x32_bf16(af[i], bff[j], acc[i][j], 0, 0, 0);
  }

  int col = lane & 15, rb = (lane >> 4) * 4;
  for (int fi = 0; fi < 4; ++fi) for (int fj = 0; fj < 4; ++fj) {
    int n = bn*BN + wn*64 + fj*16 + col;
    float bias = n < 1024 ? bfz[n] : (n < 2048 ? bfr[n-1024] : bfh[n-2048]);
    f32x4 c = acc[fi][fj];
    for (int i = 0; i < 4; ++i) {
      int m = bm*BM + wm*64 + fi*16 + rb + i;
      int bb = m >> 9, tt = m & 511;
      X[((size_t)tt*64 + bb)*3072 + n] = f2bf(c[i] + bias);
    }
  }
}

#define MFMA(a,b,c) __builtin_amdgcn_mfma_f32_16x16x32_bf16(a,b,c,0,0,0)

// ---------------- persistent recurrence: 256 wgs x 128 thr ----------------
// wave0 = round-5 compute structure (best measured: 3.44ms). wave1 = HEATER:
// spins dependent v_fma chains until wave0 sets the LDS done flag, keeping all
// 256 CUs busy so the DVFS governor holds a high clock state. Experiment:
// isolates whether the 6.7us/step plateau is down-clock-inflated latency.
__global__ __launch_bounds__(128, 1) void recur(
  const short* __restrict__ X,    // [512][64][3072] bf16
  const short* __restrict__ Wzr,  // [2048][1024] bf16
  const short* __restrict__ Wh,   // [1024][1024] bf16
  const float* __restrict__ h0,
  const float* __restrict__ buz, const float* __restrict__ bur, const float* __restrict__ buh,
  short* hb,                      // [2][64][1024] bf16 h
  short* rh,                      // [64][1024] bf16 r*h
  float* y, float* hlast, int* bar)
{
  __shared__ __align__(16) short Wl[3*32*64*8];   // 98304 B -> 1 wg per CU
  __shared__ int done;

  int tid = threadIdx.x;
  int wv = tid >> 6, lane = tid & 63;

  if (tid == 0) done = 0;
  __syncthreads();

  if (wv == 1) {
    // ================= heater wave =================
    float a = 1.000001f, b = 0.999999f, c = 1.0000001f, d = 1.0f;
    for (;;) {
      #pragma unroll
      for (int i = 0; i < 128; ++i) {
        a = __builtin_fmaf(a, b, c);
        d = __builtin_fmaf(d, b, c);
      }
      asm volatile("" :: "v"(a), "v"(d));
      if (__hip_atomic_load(&done, __ATOMIC_RELAXED, __HIP_MEMORY_SCOPE_WORKGROUP)) break;
    }
    return;
  }

  // ================= compute wave (round-5 structure verbatim) =================
  int wg = blockIdx.x;
  int cg = wg & 63, bg = wg >> 6;
  int col = lane & 15, hi = lane >> 4;
  int rb = hi*4, kfo = hi*8;
  int j  = cg*16 + col;
  int b0 = bg*16 + rb;
  int arow = bg*16 + col;

  // stage weights to LDS, fragment-ordered
  {
    const short* gbase0 = Wzr + (size_t)(cg*16 + col)*1024 + kfo;
    const short* gbase1 = Wzr + (size_t)(1024 + cg*16 + col)*1024 + kfo;
    const short* gbase2 = Wh  + (size_t)(cg*16 + col)*1024 + kfo;
    #pragma unroll 4
    for (int n = 0; n < 32; ++n) {
      *(s16x8*)(Wl + ((0*32+n)*64 + lane)*8) = *(const s16x8*)(gbase0 + n*32);
      *(s16x8*)(Wl + ((1*32+n)*64 + lane)*8) = *(const s16x8*)(gbase1 + n*32);
      *(s16x8*)(Wl + ((2*32+n)*64 + lane)*8) = *(const s16x8*)(gbase2 + n*32);
    }
  }

  float bz = buz[j], br = bur[j], bh = buh[j];
  float hreg[4], zreg[4];
  #pragma unroll
  for (int i = 0; i < 4; ++i) hreg[i] = h0[(b0+i)*1024 + j];

  unsigned short xs[12], xn[12];
  #pragma unroll
  for (int i = 0; i < 4; ++i) {
    const unsigned short* xp = (const unsigned short*)X + ((size_t)(b0+i))*3072 + j;
    xs[i] = xp[0]; xs[4+i] = xp[1024]; xs[8+i] = xp[2048];
  }

  const short* wlbase = Wl + lane*8;
  int* cnt = bar + bg*64;
  int tgt = 64;

  asm volatile("s_waitcnt vmcnt(0)" ::: "memory");

  for (int t = 0; t < 512; ++t) {
    const short* hbc = hb + (t&1)*65536;
    short* hbn = hb + ((t&1)^1)*65536;

    { // ---- phase 1: z, r ----
      const short* ap = hbc + (size_t)arow*1024 + kfo;
      s16x8 ah[32];
      cload8(ap,     ah[0], ah[1], ah[2], ah[3], ah[4], ah[5], ah[6], ah[7]);
      cload8(ap+256, ah[8], ah[9], ah[10],ah[11],ah[12],ah[13],ah[14],ah[15]);
      cload8(ap+512, ah[16],ah[17],ah[18],ah[19],ah[20],ah[21],ah[22],ah[23]);
      cload8(ap+768, ah[24],ah[25],ah[26],ah[27],ah[28],ah[29],ah[30],ah[31]);
      f32x4 acz = {0.f,0.f,0.f,0.f}, acr = {0.f,0.f,0.f,0.f};
      WAITV(24)
      #pragma unroll
      for (int n = 0; n < 8; ++n) {
        s16x8 vz = *(const s16x8*)(wlbase + n*512);
        s16x8 vr = *(const s16x8*)(wlbase + 16384 + n*512);
        acz = MFMA(ah[n], vz, acz);
        acr = MFMA(ah[n], vr, acr);
      }
      WAITV(16)
      #pragma unroll
      for (int n = 8; n < 16; ++n) {
        s16x8 vz = *(const s16x8*)(wlbase + n*512);
        s16x8 vr = *(const s16x8*)(wlbase + 16384 + n*512);
        acz = MFMA(ah[n], vz, acz);
        acr = MFMA(ah[n], vr, acr);
      }
      WAITV(8)
      #pragma unroll
      for (int n = 16; n < 24; ++n) {
        s16x8 vz = *(const s16x8*)(wlbase + n*512);
        s16x8 vr = *(const s16x8*)(wlbase + 16384 + n*512);
        acz = MFMA(ah[n], vz, acz);
        acr = MFMA(ah[n], vr, acr);
      }
      WAITV(0)
      #pragma unroll
      for (int n = 24; n < 32; ++n) {
        s16x8 vz = *(const s16x8*)(wlbase + n*512);
        s16x8 vr = *(const s16x8*)(wlbase + 16384 + n*512);
        acz = MFMA(ah[n], vz, acz);
        acr = MFMA(ah[n], vr, acr);
      }
      #pragma unroll
      for (int i = 0; i < 4; ++i) {
        zreg[i] = sigm(bf2f(xs[i]) + acz[i] + bz);
        float r = sigm(bf2f(xs[4+i]) + acr[i] + br);
        __hip_atomic_store(rh + (b0+i)*1024 + j, f2bf(r * hreg[i]),
                           __ATOMIC_RELAXED, __HIP_MEMORY_SCOPE_AGENT);
      }
    }
    // barrier: drain data stores, fire-and-forget arrival, broadcast poll
    asm volatile("s_waitcnt vmcnt(0)" ::: "memory");
    if (lane == 0)
      __hip_atomic_fetch_add(cnt, 1, __ATOMIC_RELAXED, __HIP_MEMORY_SCOPE_AGENT);
    {
      int v;
      do { v = __hip_atomic_load(cnt, __ATOMIC_RELAXED, __HIP_MEMORY_SCOPE_AGENT); }
      while (v < tgt);
      tgt += 64;
    }

    { // ---- phase 2: h_hat, combine ----
      const short* ap = rh + (size_t)arow*1024 + kfo;
      s16x8 ah[32];
      cload8(ap,     ah[0], ah[1], ah[2], ah[3], ah[4], ah[5], ah[6], ah[7]);
      cload8(ap+256, ah[8], ah[9], ah[10],ah[11],ah[12],ah[13],ah[14],ah[15]);
      cload8(ap+512, ah[16],ah[17],ah[18],ah[19],ah[20],ah[21],ah[22],ah[23]);
      cload8(ap+768, ah[24],ah[25],ah[26],ah[27],ah[28],ah[29],ah[30],ah[31]);
      f32x4 ach = {0.f,0.f,0.f,0.f};
      WAITV(24)
      #pragma unroll
      for (int n = 0; n < 8; ++n)
        ach = MFMA(ah[n], *(const s16x8*)(wlbase + 32768 + n*512), ach);
      WAITV(16)
      #pragma unroll
      for (int n = 8; n < 16; ++n)
        ach = MFMA(ah[n], *(const s16x8*)(wlbase + 32768 + n*512), ach);
      WAITV(8)
      #pragma unroll
      for (int n = 16; n < 24; ++n)
        ach = MFMA(ah[n], *(const s16x8*)(wlbase + 32768 + n*512), ach);
      WAITV(0)
      #pragma unroll
      for (int n = 24; n < 32; ++n)
        ach = MFMA(ah[n], *(const s16x8*)(wlbase + 32768 + n*512), ach);
      float hnv[4];
      #pragma unroll
      for (int i = 0; i < 4; ++i) {
        float s  = bf2f(xs[8+i]) + ach[i] + bh;
        float hh = s * sigm(s);
        float hn = (1.0f - zreg[i])*hreg[i] + zreg[i]*hh;
        hnv[i] = hn; hreg[i] = hn;
        __hip_atomic_store(hbn + (b0+i)*1024 + j, f2bf(hn),
                           __ATOMIC_RELAXED, __HIP_MEMORY_SCOPE_AGENT);
      }
      // barrier: drain h stores, arrive
      asm volatile("s_waitcnt vmcnt(0)" ::: "memory");
      if (lane == 0)
        __hip_atomic_fetch_add(cnt, 1, __ATOMIC_RELAXED, __HIP_MEMORY_SCOPE_AGENT);
      // off-critical-path work in the poll shadow: y stores, X prefetch, hlast
      #pragma unroll
      for (int i = 0; i < 4; ++i)
        __builtin_nontemporal_store(hnv[i], y + ((size_t)(b0+i)*512 + t)*1024 + j);
      int tn = (t+1) & 511;
      #pragma unroll
      for (int i = 0; i < 4; ++i) {
        const unsigned short* xp = (const unsigned short*)X + ((size_t)tn*64 + (b0+i))*3072 + j;
        xn[i] = xp[0]; xn[4+i] = xp[1024]; xn[8+i] = xp[2048];
      }
      if (t == 511) {
        #pragma unroll
        for (int i = 0; i < 4; ++i) hlast[(b0+i)*1024 + j] = hreg[i];
      }
      {
        int v;
        do { v = __hip_atomic_load(cnt, __ATOMIC_RELAXED, __HIP_MEMORY_SCOPE_AGENT); }
        while (v < tgt);
        tgt += 64;
      }
    }

    #pragma unroll
    for (int q = 0; q < 12; ++q) xs[q] = xn[q];
  }

  // stop the heater
  __hip_atomic_store(&done, 1, __ATOMIC_RELAXED, __HIP_MEMORY_SCOPE_WORKGROUP);
}

extern "C" void kernel_launch(void* const* d_in, const int* in_sizes, int n_in,
                              void* d_out, int out_size, void* d_ws, size_t ws_size,
                              hipStream_t stream) {
  const float* x   = (const float*)d_in[0];
  const float* h0  = (const float*)d_in[1];
  const float* Wfz = (const float*)d_in[2];
  const float* bfz = (const float*)d_in[3];
  const float* Wfr = (const float*)d_in[4];
  const float* bfr = (const float*)d_in[5];
  const float* Wfh = (const float*)d_in[6];
  const float* bfh = (const float*)d_in[7];
  const float* Wuz = (const float*)d_in[8];
  const float* buz = (const float*)d_in[9];
  const float* Wur = (const float*)d_in[10];
  const float* bur = (const float*)d_in[11];
  const float* Wuh = (const float*)d_in[12];
  const float* buh = (const float*)d_in[13];

  char* ws = (char*)d_ws;
  short* Xb  = (short*)(ws);                  // 201326592 B  [512][64][3072] bf16
  short* xb  = (short*)(ws + 201326592);      //  67108864 B
  short* Wf  = (short*)(ws + 268435456);      //   6291456 B
  short* Wzr = (short*)(ws + 274726912);      //   4194304 B
  short* Wh  = (short*)(ws + 278921216);      //   2097152 B
  short* hb  = (short*)(ws + 281018368);      //    262144 B
  short* rh  = (short*)(ws + 281280512);      //    131072 B
  int*   bar = (int*)(ws + 281411584);        //    1024 B counters[4 domains]

  float* y = (float*)d_out;
  float* hlast = y + 33554432;

  hipMemsetAsync(bar, 0, 1024, stream);
  prep<<<2048, 256, 0, stream>>>(x, Wfz, Wfr, Wfh, Wuz, Wur, Wuh, h0, xb, Wf, Wzr, Wh, hb);
  gemm_x<<<6144, 256, 0, stream>>>(xb, Wf, bfz, bfr, bfh, Xb);
  recur<<<256, 128, 0, stream>>>(Xb, Wzr, Wh, h0, buz, bur, buh, hb, rh, y, hlast, bar);
}